// Round 1
// baseline (3368.445 us; speedup 1.0000x reference)
//
#include <hip/hip_runtime.h>

typedef __attribute__((ext_vector_type(4))) float  f32x4;
typedef __attribute__((ext_vector_type(8))) short  short8;
typedef __attribute__((ext_vector_type(4))) int    i32x4;
typedef __attribute__((ext_vector_type(2))) int    i32x2;

#define LOG2E 1.4426950408889634f

__device__ __forceinline__ float fexp2(float x){ float r; asm("v_exp_f32 %0, %1" : "=v"(r) : "v"(x)); return r; }
__device__ __forceinline__ float frcp (float x){ float r; asm("v_rcp_f32 %0, %1" : "=v"(r) : "v"(x)); return r; }
__device__ __forceinline__ float fsigmoid(float x){ return frcp(1.f + fexp2(-LOG2E*x)); }
__device__ __forceinline__ float ftanhf (float x){ return 1.f - 2.f*frcp(1.f + fexp2(2.f*LOG2E*x)); }

__device__ __forceinline__ unsigned short f2bf(float f){
  unsigned u = __builtin_bit_cast(unsigned, f);
  u = u + 0x7FFFu + ((u >> 16) & 1u);
  return (unsigned short)(u >> 16);
}
__device__ __forceinline__ float bf2f(unsigned short h){
  unsigned u = ((unsigned)h) << 16;
  return __builtin_bit_cast(float, u);
}

// ---------------- prep kernels ----------------
__global__ void cast_f32_bf16(const float* __restrict__ s, unsigned short* __restrict__ d, int n4){
  int i = blockIdx.x * 256 + threadIdx.x;
  int stride = gridDim.x * 256;
  for (; i < n4; i += stride){
    float4 f = ((const float4*)s)[i];
    uint2 o;
    o.x = (unsigned)f2bf(f.x) | ((unsigned)f2bf(f.y) << 16);
    o.y = (unsigned)f2bf(f.z) | ((unsigned)f2bf(f.w) << 16);
    ((uint2*)d)[i] = o;
  }
}

// W1 (10 x 1024) -> padded 64x512 bf16: rows 0..9 = W1[:, :512] (q), rows 16..25 = W1[:, 512:] (k), rest 0
__global__ void pack_w1(const float* __restrict__ W1, unsigned short* __restrict__ d){
  int i = blockIdx.x * 256 + threadIdx.x;   // 0..32767
  int r = i >> 9, c = i & 511;
  float v = 0.f;
  if (r < 10) v = W1[r * 1024 + c];
  else if (r >= 16 && r < 26) v = W1[(r - 16) * 1024 + 512 + c];
  d[i] = f2bf(v);
}

__global__ void pack_bias(const float* __restrict__ bif, const float* __restrict__ bhf,
                          const float* __restrict__ bib, const float* __restrict__ bhb,
                          float* __restrict__ d){
  int i = blockIdx.x * 1024 + threadIdx.x;
  if (i < 1024) d[i] = bif[i] + bhf[i];
  else          d[i] = bib[i - 1024] + bhb[i - 1024];
}

// ---------------- generic bf16 GEMM: C[M,N] = A[M,K] @ B[N,K]^T (+bias) ----------------
// 128x128 tile, BK=32, 256 threads, 4 waves in 2x2, each wave 4x4 tiles of 16x16x32 MFMA.
__global__ __launch_bounds__(256) void gemm_abt(
    const unsigned short* __restrict__ A, long lda, long sAz,
    const unsigned short* __restrict__ B, long ldb, long sBz,
    const float* __restrict__ bias,
    void* __restrict__ Cv, long ldc, long sCz,
    int M, int N, int K, int obf16)
{
  __shared__ __align__(16) unsigned short As[128 * 40];
  __shared__ __align__(16) unsigned short Bs[128 * 40];
  const int tid = threadIdx.x;
  const int m0 = blockIdx.y * 128;
  const int n0 = blockIdx.x * 128;
  const long z = blockIdx.z;
  A += z * sAz; B += z * sBz;
  const int w = tid >> 6, l = tid & 63;
  const int wm = (w >> 1) * 64, wn = (w & 1) * 64;
  const int lm = l & 15, lq = l >> 4;
  f32x4 acc[4][4] = {};
  const int sr = tid >> 1;           // staging row 0..127
  const int sk = (tid & 1) * 16;     // staging col offset (elements)
  const unsigned short* Aptr = A + (long)(m0 + sr) * lda + sk;
  const unsigned short* Bptr = B + (long)(n0 + sr) * ldb + sk;
  const bool bvalid = (n0 + sr) < N;
  const int KB = K >> 5;
  for (int kb = 0; kb < KB; ++kb){
    i32x4 av0 = *(const i32x4*)(Aptr);
    i32x4 av1 = *(const i32x4*)(Aptr + 8);
    i32x4 bv0 = {0,0,0,0}, bv1 = {0,0,0,0};
    if (bvalid){ bv0 = *(const i32x4*)(Bptr); bv1 = *(const i32x4*)(Bptr + 8); }
    Aptr += 32; Bptr += 32;
    __syncthreads();
    *(i32x4*)&As[sr * 40 + sk] = av0;  *(i32x4*)&As[sr * 40 + sk + 8] = av1;
    *(i32x4*)&Bs[sr * 40 + sk] = bv0;  *(i32x4*)&Bs[sr * 40 + sk + 8] = bv1;
    __syncthreads();
    const int koff = lq * 8;
    short8 af[4], bf[4];
    #pragma unroll
    for (int mt = 0; mt < 4; ++mt) af[mt] = *(short8*)&As[(wm + mt * 16 + lm) * 40 + koff];
    #pragma unroll
    for (int nt = 0; nt < 4; ++nt) bf[nt] = *(short8*)&Bs[(wn + nt * 16 + lm) * 40 + koff];
    #pragma unroll
    for (int mt = 0; mt < 4; ++mt)
      #pragma unroll
      for (int nt = 0; nt < 4; ++nt)
        acc[mt][nt] = __builtin_amdgcn_mfma_f32_16x16x32_bf16(af[mt], bf[nt], acc[mt][nt], 0, 0, 0);
  }
  #pragma unroll
  for (int mt = 0; mt < 4; ++mt){
    const int mbase = m0 + wm + mt * 16 + lq * 4;
    #pragma unroll
    for (int nt = 0; nt < 4; ++nt){
      const int n = n0 + wn + nt * 16 + lm;
      if (n < N){
        const float bv = bias ? bias[n] : 0.f;
        #pragma unroll
        for (int r = 0; r < 4; ++r){
          const float v = acc[mt][nt][r] + bv;
          const long idx = z * sCz + (long)(mbase + r) * ldc + n;
          if (obf16) ((unsigned short*)Cv)[idx] = f2bf(v);
          else       ((float*)Cv)[idx] = v;
        }
      }
    }
  }
}

// ---------------- LSTM scan ----------------
// 32 blocks x 256 threads. block = (dir d = bid&1, slice g = bid>>1 of 16 hidden units).
// Wave w = gate (i,f,g,o). Whh slice register-resident as MFMA B-frags.
// h exchange: tagged qwords (lo32 = 0x5A000000+t, hi32 = 2 bf16) via sc0/sc1 (device-scope) loads/stores.
__global__ __launch_bounds__(256) void lstm_scan(
    const unsigned short* __restrict__ xg,   // [8192][2048] bf16, row = b*1024+t, col = d*1024+q*256+j
    const float* __restrict__ Whh_f, const float* __restrict__ Whh_b,
    unsigned long long* __restrict__ hex_,   // [2][1024][8][128] qwords
    unsigned short* __restrict__ hcat,       // [8][1024][1024] bf16 (cols 0..511 written here)
    unsigned short* __restrict__ hT)         // [8][512][1024] bf16 (transposed h)
{
  const int d  = blockIdx.x & 1;
  const int g  = blockIdx.x >> 1;
  const int tid = threadIdx.x;
  const int w  = tid >> 6;
  const int l  = tid & 63;
  const int lm = l & 15;
  const int lq = l >> 4;
  const float* Whh = d ? Whh_b : Whh_f;

  __shared__ __align__(16) float gbuf[4 * 16 * 8];  // [gate][j(16)][b(8)]

  // resident B fragments: lane lm = n (j_local), k = lq*8 + kt*32 + 0..7
  short8 bfr[8];
  {
    const float* wr = Whh + (long)(w * 256 + g * 16 + lm) * 256 + lq * 8;
    #pragma unroll
    for (int kt = 0; kt < 8; ++kt){
      float4 f0 = *(const float4*)(wr + kt * 32);
      float4 f1 = *(const float4*)(wr + kt * 32 + 4);
      i32x4 p;
      p.x = (unsigned)f2bf(f0.x) | ((unsigned)f2bf(f0.y) << 16);
      p.y = (unsigned)f2bf(f0.z) | ((unsigned)f2bf(f0.w) << 16);
      p.z = (unsigned)f2bf(f1.x) | ((unsigned)f2bf(f1.y) << 16);
      p.w = (unsigned)f2bf(f1.z) | ((unsigned)f2bf(f1.w) << 16);
      bfr[kt] = __builtin_bit_cast(short8, p);
    }
  }

  const bool bval = lm < 8;       // A-operand carrier lanes (b = lm)
  i32x4 q[16];
  #pragma unroll
  for (int i = 0; i < 16; ++i) q[i] = i32x4{0,0,0,0};

  const int gb = tid >> 4;        // gate-phase b (tid<128)
  const int gj = tid & 15;        // gate-phase j_local
  float c_state = 0.f;

  for (int t = 0; t < 1024; ++t){
    const int t_x = d ? (1023 - t) : t;
    float xgi = 0.f, xgf = 0.f, xgg = 0.f, xgo = 0.f;
    if (tid < 128){
      const unsigned short* xr = xg + (long)(gb * 1024 + t_x) * 2048 + d * 1024 + g * 16 + gj;
      xgi = bf2f(xr[0]); xgf = bf2f(xr[256]); xgg = bf2f(xr[512]); xgo = bf2f(xr[768]);
    }
    f32x4 acc0 = {0.f,0.f,0.f,0.f}, acc1 = {0.f,0.f,0.f,0.f};
    if (t > 0){
      const char* bptr = (const char*)(hex_ + (((long)d * 1024 + (t - 1)) * 8 + lm) * 128 + lq * 4);
      const int tag = 0x5A000000 + (t - 1);
      int tries = 0; bool ok;
#define LQ(i, o) asm volatile("global_load_dwordx4 %0, %1, off offset:" #o " sc0 sc1" : "=v"(q[i]) : "v"(bptr) : "memory")
      do {
        if (bval){
          LQ(0,0);    LQ(1,16);   LQ(2,128);  LQ(3,144);
          LQ(4,256);  LQ(5,272);  LQ(6,384);  LQ(7,400);
          LQ(8,512);  LQ(9,528);  LQ(10,640); LQ(11,656);
          LQ(12,768); LQ(13,784); LQ(14,896); LQ(15,912);
        }
        asm volatile("s_waitcnt vmcnt(0)" ::: "memory");
        bool myok = true;
        if (bval){
          #pragma unroll
          for (int i = 0; i < 16; ++i) myok = myok && (q[i].x == tag) && (q[i].z == tag);
        }
        ok = (bool)__all((int)myok);
      } while (!ok && ++tries < (1 << 14));
#undef LQ
      #pragma unroll
      for (int kt = 0; kt < 8; ++kt){
        i32x4 aw;
        aw.x = q[2*kt].y;   aw.y = q[2*kt].w;
        aw.z = q[2*kt+1].y; aw.w = q[2*kt+1].w;
        short8 af = __builtin_bit_cast(short8, aw);
        if (kt & 1) acc1 = __builtin_amdgcn_mfma_f32_16x16x32_bf16(af, bfr[kt], acc1, 0, 0, 0);
        else        acc0 = __builtin_amdgcn_mfma_f32_16x16x32_bf16(af, bfr[kt], acc0, 0, 0, 0);
      }
    }
    f32x4 asum = acc0 + acc1;
    if (l < 32){
      *(f32x4*)&gbuf[(w * 16 + lm) * 8 + lq * 4] = asum;   // C[b=lq*4+r][j=lm]
    }
    __syncthreads();
    if (tid < 128){
      const float gi = gbuf[(0 * 16 + gj) * 8 + gb] + xgi;
      const float gf = gbuf[(1 * 16 + gj) * 8 + gb] + xgf;
      const float gg = gbuf[(2 * 16 + gj) * 8 + gb] + xgg;
      const float go = gbuf[(3 * 16 + gj) * 8 + gb] + xgo;
      c_state = fsigmoid(gf) * c_state + fsigmoid(gi) * ftanhf(gg);
      const float h = fsigmoid(go) * ftanhf(c_state);
      const unsigned short hb = f2bf(h);
      hcat[(long)(gb * 1024 + t_x) * 1024 + d * 256 + g * 16 + gj] = hb;
      hT[(long)(gb * 512 + d * 256 + g * 16 + gj) * 1024 + t_x] = hb;
      const int other = __shfl_xor((int)hb, 1);
      if (!(gj & 1)){
        i32x2 st2;
        st2.x = 0x5A000000 + t;
        st2.y = (int)(((unsigned)hb) | (((unsigned)other) << 16));
        unsigned long long* sp = hex_ + (((long)d * 1024 + t) * 8 + gb) * 128 + (g * 16 + gj) / 2;
        asm volatile("global_store_dwordx2 %0, %1, off sc0 sc1" :: "v"(sp), "v"(st2) : "memory");
      }
    }
    __syncthreads();
  }
}

// ---------------- attention scores + softmax ----------------
// block = (b,t); scores s[u] = sum_x W2[x] * tanh(qp[t,x] + kp[u,x]); softmax over u with mask.
__global__ __launch_bounds__(256) void attn_scores(
    const float* __restrict__ qk,   // [8192][64]: qp at cols 0..9, kp at cols 16..25
    const float* __restrict__ W2,   // [10]
    const int*   __restrict__ mask, // [8][1024]
    unsigned short* __restrict__ attn) // [8][1024][1024] bf16
{
  const int bt = blockIdx.x;
  const int b = bt >> 10;
  const int tid = threadIdx.x;
  __shared__ float red[256];
  float qv[10], w2[10];
  const float* qrow = qk + (long)bt * 64;
  #pragma unroll
  for (int x = 0; x < 10; ++x){ qv[x] = qrow[x]; w2[x] = W2[x]; }
  float sv[4];
  float smax = -3.4e38f;
  #pragma unroll
  for (int uu = 0; uu < 4; ++uu){
    const int u = tid + uu * 256;
    const float* krow = qk + (long)(b * 1024 + u) * 64 + 16;
    float s = 0.f;
    #pragma unroll
    for (int x = 0; x < 10; ++x) s += w2[x] * ftanhf(qv[x] + krow[x]);
    if (mask[b * 1024 + u] == 0) s = -3.0e38f;
    sv[uu] = s;
    smax = fmaxf(smax, s);
  }
  red[tid] = smax; __syncthreads();
  for (int off = 128; off > 0; off >>= 1){
    if (tid < off) red[tid] = fmaxf(red[tid], red[tid + off]);
    __syncthreads();
  }
  const float mx = red[0]; __syncthreads();
  float ev[4]; float lsum = 0.f;
  #pragma unroll
  for (int uu = 0; uu < 4; ++uu){ ev[uu] = fexp2((sv[uu] - mx) * LOG2E); lsum += ev[uu]; }
  red[tid] = lsum; __syncthreads();
  for (int off = 128; off > 0; off >>= 1){
    if (tid < off) red[tid] = red[tid] + red[tid + off];
    __syncthreads();
  }
  const float inv = frcp(red[0]);
  #pragma unroll
  for (int uu = 0; uu < 4; ++uu)
    attn[(long)bt * 1024 + tid + uu * 256] = f2bf(ev[uu] * inv);
}

// ---------------- launch ----------------
extern "C" void kernel_launch(void* const* d_in, const int* in_sizes, int n_in,
                              void* d_out, int out_size, void* d_ws, size_t ws_size,
                              hipStream_t stream) {
  (void)in_sizes; (void)n_in; (void)out_size; (void)ws_size;
  const float* x     = (const float*)d_in[0];
  const int*   mask  = (const int*)d_in[1];
  const float* Wih_f = (const float*)d_in[3];
  const float* Whh_f = (const float*)d_in[4];
  const float* bih_f = (const float*)d_in[5];
  const float* bhh_f = (const float*)d_in[6];
  const float* Wih_b = (const float*)d_in[7];
  const float* Whh_b = (const float*)d_in[8];
  const float* bih_b = (const float*)d_in[9];
  const float* bhh_b = (const float*)d_in[10];
  const float* W1    = (const float*)d_in[11];
  const float* W2    = (const float*)d_in[12];
  const float* W3    = (const float*)d_in[13];
  const float* b3    = (const float*)d_in[14];

  char* W = (char*)d_ws;
  unsigned short* x_bf    = (unsigned short*)(W + 0);          // 12,582,912
  unsigned short* wihcat  = (unsigned short*)(W + 12582912);   //  3,145,728
  unsigned short* w3bf    = (unsigned short*)(W + 15728640);   //  1,048,576
  unsigned short* w1p     = (unsigned short*)(W + 16777216);   //     65,536
  float*          bc      = (float*)        (W + 16842752);    //      8,192
  unsigned short* xg      = (unsigned short*)(W + 16850944);   // 33,554,432
  unsigned long long* hex_= (unsigned long long*)(W + 50405376); // 16,777,216
  unsigned short* hcat    = (unsigned short*)(W + 67182592);   // 16,777,216
  unsigned short* hT      = (unsigned short*)(W + 83959808);   //  8,388,608
  float*          qk      = (float*)        (W + 92348416);    //  2,097,152
  unsigned short* attn    = (unsigned short*)(W + 94445568);   // 16,777,216 -> total 111,222,784

  // prep
  cast_f32_bf16<<<6144, 256, 0, stream>>>(x, x_bf, 1572864);
  cast_f32_bf16<<<768,  256, 0, stream>>>(Wih_f, wihcat, 196608);
  cast_f32_bf16<<<768,  256, 0, stream>>>(Wih_b, wihcat + 786432, 196608);
  cast_f32_bf16<<<512,  256, 0, stream>>>(W3, w3bf, 131072);
  pack_w1 <<<128, 256, 0, stream>>>(W1, w1p);
  pack_bias<<<2, 1024, 0, stream>>>(bih_f, bhh_f, bih_b, bhh_b, bc);

  // xg = x @ [Wih_f;Wih_b]^T + bias  -> bf16 [8192][2048]
  gemm_abt<<<dim3(16, 64, 1), 256, 0, stream>>>(x_bf, 768, 0, wihcat, 768, 0, bc,
                                                xg, 2048, 0, 8192, 2048, 768, 1);
  // BiLSTM scan
  lstm_scan<<<32, 256, 0, stream>>>(xg, Whh_f, Whh_b, hex_, hcat, hT);

  // qp/kp: hcat[:, :512] @ W1pack^T -> qk fp32 [8192][64]
  gemm_abt<<<dim3(1, 64, 1), 256, 0, stream>>>(hcat, 1024, 0, w1p, 512, 0, nullptr,
                                               qk, 64, 0, 8192, 64, 512, 0);
  // scores + softmax -> attn bf16
  attn_scores<<<8192, 256, 0, stream>>>(qk, W2, mask, attn);

  // context = attn @ h (per b): A=attn[b], B=hT[b] (512x1024) -> hcat[:, 512:]
  gemm_abt<<<dim3(4, 8, 8), 256, 0, stream>>>(attn, 1024, 1048576, hT, 1024, 524288, nullptr,
                                              (void*)(hcat + 512), 1024, 1048576, 1024, 512, 1024, 1);
  // y = [h|ctx] @ W3^T + b3 -> d_out fp32
  gemm_abt<<<dim3(4, 64, 1), 256, 0, stream>>>(hcat, 1024, 0, w3bf, 1024, 0, b3,
                                               (float*)d_out, 512, 0, 8192, 512, 1024, 0);
}

// Round 2
// 2598.045 us; speedup vs baseline: 1.2965x; 1.2965x over previous
//
#include <hip/hip_runtime.h>

typedef __attribute__((ext_vector_type(4))) float  f32x4;
typedef __attribute__((ext_vector_type(8))) short  short8;
typedef __attribute__((ext_vector_type(4))) int    i32x4;
typedef __attribute__((ext_vector_type(2))) int    i32x2;

#define LOG2E 1.4426950408889634f

__device__ __forceinline__ float fexp2(float x){ float r; asm("v_exp_f32 %0, %1" : "=v"(r) : "v"(x)); return r; }
__device__ __forceinline__ float frcp (float x){ float r; asm("v_rcp_f32 %0, %1" : "=v"(r) : "v"(x)); return r; }
__device__ __forceinline__ float fsigmoid(float x){ return frcp(1.f + fexp2(-LOG2E*x)); }
__device__ __forceinline__ float ftanhf (float x){ return 1.f - 2.f*frcp(1.f + fexp2(2.f*LOG2E*x)); }

__device__ __forceinline__ unsigned short f2bf(float f){
  unsigned u = __builtin_bit_cast(unsigned, f);
  u = u + 0x7FFFu + ((u >> 16) & 1u);
  return (unsigned short)(u >> 16);
}
__device__ __forceinline__ float bf2f(unsigned short h){
  unsigned u = ((unsigned)h) << 16;
  return __builtin_bit_cast(float, u);
}

// ---------------- prep kernels ----------------
__global__ void cast_f32_bf16(const float* __restrict__ s, unsigned short* __restrict__ d, int n4){
  int i = blockIdx.x * 256 + threadIdx.x;
  int stride = gridDim.x * 256;
  for (; i < n4; i += stride){
    float4 f = ((const float4*)s)[i];
    uint2 o;
    o.x = (unsigned)f2bf(f.x) | ((unsigned)f2bf(f.y) << 16);
    o.y = (unsigned)f2bf(f.z) | ((unsigned)f2bf(f.w) << 16);
    ((uint2*)d)[i] = o;
  }
}

// W1 (10 x 1024) -> padded 64x512 bf16: rows 0..9 = W1[:, :512] (q), rows 16..25 = W1[:, 512:] (k), rest 0
__global__ void pack_w1(const float* __restrict__ W1, unsigned short* __restrict__ d){
  int i = blockIdx.x * 256 + threadIdx.x;   // 0..32767
  int r = i >> 9, c = i & 511;
  float v = 0.f;
  if (r < 10) v = W1[r * 1024 + c];
  else if (r >= 16 && r < 26) v = W1[(r - 16) * 1024 + 512 + c];
  d[i] = f2bf(v);
}

__global__ void pack_bias(const float* __restrict__ bif, const float* __restrict__ bhf,
                          const float* __restrict__ bib, const float* __restrict__ bhb,
                          float* __restrict__ d){
  int i = blockIdx.x * 1024 + threadIdx.x;
  if (i < 1024) d[i] = bif[i] + bhf[i];
  else          d[i] = bib[i - 1024] + bhb[i - 1024];
}

// ---------------- generic bf16 GEMM: C[M,N] = A[M,K] @ B[N,K]^T (+bias) ----------------
__global__ __launch_bounds__(256) void gemm_abt(
    const unsigned short* __restrict__ A, long lda, long sAz,
    const unsigned short* __restrict__ B, long ldb, long sBz,
    const float* __restrict__ bias,
    void* __restrict__ Cv, long ldc, long sCz,
    int M, int N, int K, int obf16)
{
  __shared__ __align__(16) unsigned short As[128 * 40];
  __shared__ __align__(16) unsigned short Bs[128 * 40];
  const int tid = threadIdx.x;
  const int m0 = blockIdx.y * 128;
  const int n0 = blockIdx.x * 128;
  const long z = blockIdx.z;
  A += z * sAz; B += z * sBz;
  const int w = tid >> 6, l = tid & 63;
  const int wm = (w >> 1) * 64, wn = (w & 1) * 64;
  const int lm = l & 15, lq = l >> 4;
  f32x4 acc[4][4] = {};
  const int sr = tid >> 1;
  const int sk = (tid & 1) * 16;
  const unsigned short* Aptr = A + (long)(m0 + sr) * lda + sk;
  const unsigned short* Bptr = B + (long)(n0 + sr) * ldb + sk;
  const bool bvalid = (n0 + sr) < N;
  const int KB = K >> 5;
  for (int kb = 0; kb < KB; ++kb){
    i32x4 av0 = *(const i32x4*)(Aptr);
    i32x4 av1 = *(const i32x4*)(Aptr + 8);
    i32x4 bv0 = {0,0,0,0}, bv1 = {0,0,0,0};
    if (bvalid){ bv0 = *(const i32x4*)(Bptr); bv1 = *(const i32x4*)(Bptr + 8); }
    Aptr += 32; Bptr += 32;
    __syncthreads();
    *(i32x4*)&As[sr * 40 + sk] = av0;  *(i32x4*)&As[sr * 40 + sk + 8] = av1;
    *(i32x4*)&Bs[sr * 40 + sk] = bv0;  *(i32x4*)&Bs[sr * 40 + sk + 8] = bv1;
    __syncthreads();
    const int koff = lq * 8;
    short8 af[4], bf[4];
    #pragma unroll
    for (int mt = 0; mt < 4; ++mt) af[mt] = *(short8*)&As[(wm + mt * 16 + lm) * 40 + koff];
    #pragma unroll
    for (int nt = 0; nt < 4; ++nt) bf[nt] = *(short8*)&Bs[(wn + nt * 16 + lm) * 40 + koff];
    #pragma unroll
    for (int mt = 0; mt < 4; ++mt)
      #pragma unroll
      for (int nt = 0; nt < 4; ++nt)
        acc[mt][nt] = __builtin_amdgcn_mfma_f32_16x16x32_bf16(af[mt], bf[nt], acc[mt][nt], 0, 0, 0);
  }
  #pragma unroll
  for (int mt = 0; mt < 4; ++mt){
    const int mbase = m0 + wm + mt * 16 + lq * 4;
    #pragma unroll
    for (int nt = 0; nt < 4; ++nt){
      const int n = n0 + wn + nt * 16 + lm;
      if (n < N){
        const float bv = bias ? bias[n] : 0.f;
        #pragma unroll
        for (int r = 0; r < 4; ++r){
          const float v = acc[mt][nt][r] + bv;
          const long idx = z * sCz + (long)(mbase + r) * ldc + n;
          if (obf16) ((unsigned short*)Cv)[idx] = f2bf(v);
          else       ((float*)Cv)[idx] = v;
        }
      }
    }
  }
}

// ---------------- LSTM scan (flag/data split exchange) ----------------
// 32 blocks x 256 threads. block = (dir d = bid&1, slice g = bid>>1 of 16 hidden units).
// Wave w = gate (i,f,g,o). Whh slice register-resident as MFMA B-frags.
// hexd[d][t][b(8)][k(256)] bf16 data; flags[d][t][rep(4)][256] ints (tag = 0x5A000000+t).
// Producer thread i<16: store 16B data chunk sc0sc1, vmcnt(0), store its flag to 4 replicas.
// Consumer wave w: poll replica w (one coalesced dwordx4/lane), then one-shot load A-frags.
__global__ __launch_bounds__(256) void lstm_scan(
    const unsigned short* __restrict__ xg,   // [8192][2048] bf16, row = b*1024+t, col = d*1024+q*256+j
    const float* __restrict__ Whh_f, const float* __restrict__ Whh_b,
    unsigned short* __restrict__ hexd,       // [2][1024][8][256] bf16
    int* __restrict__ flags,                 // [2][1024][4][256]
    unsigned short* __restrict__ hcat,       // [8][1024][1024] bf16 (cols 0..511 written here)
    unsigned short* __restrict__ hT)         // [8][512][1024] bf16 (transposed h)
{
  const int d  = blockIdx.x & 1;
  const int g  = blockIdx.x >> 1;
  const int tid = threadIdx.x;
  const int w  = tid >> 6;
  const int l  = tid & 63;
  const int lm = l & 15;
  const int lq = l >> 4;
  const float* Whh = d ? Whh_b : Whh_f;

  __shared__ __align__(16) float gbuf[4 * 16 * 8];       // [gate][j(16)][b(8)]
  __shared__ __align__(16) unsigned short hsh[128];      // [b(8)][j(16)]

  // resident B fragments: lane lm = n (j_local), k = lq*8 + kt*32 + 0..7
  short8 bfr[8];
  {
    const float* wr = Whh + (long)(w * 256 + g * 16 + lm) * 256 + lq * 8;
    #pragma unroll
    for (int kt = 0; kt < 8; ++kt){
      float4 f0 = *(const float4*)(wr + kt * 32);
      float4 f1 = *(const float4*)(wr + kt * 32 + 4);
      i32x4 p;
      p.x = (unsigned)f2bf(f0.x) | ((unsigned)f2bf(f0.y) << 16);
      p.y = (unsigned)f2bf(f0.z) | ((unsigned)f2bf(f0.w) << 16);
      p.z = (unsigned)f2bf(f1.x) | ((unsigned)f2bf(f1.y) << 16);
      p.w = (unsigned)f2bf(f1.z) | ((unsigned)f2bf(f1.w) << 16);
      bfr[kt] = __builtin_bit_cast(short8, p);
    }
  }

  const bool bval = lm < 8;       // A-operand carrier lanes (b = lm)
  const int gb = tid >> 4;        // gate-phase b (tid<128)
  const int gj = tid & 15;        // gate-phase j_local
  float c_state = 0.f;

  for (int t = 0; t < 1024; ++t){
    const int t_x = d ? (1023 - t) : t;
    // xg prefetch (issued before the poll so latency overlaps the wait)
    float xgi = 0.f, xgf = 0.f, xgg = 0.f, xgo = 0.f;
    if (tid < 128){
      const unsigned short* xr = xg + (long)(gb * 1024 + t_x) * 2048 + d * 1024 + g * 16 + gj;
      xgi = bf2f(xr[0]); xgf = bf2f(xr[256]); xgg = bf2f(xr[512]); xgo = bf2f(xr[768]);
    }
    f32x4 acc0 = {0.f,0.f,0.f,0.f}, acc1 = {0.f,0.f,0.f,0.f};
    if (t > 0){
      const int tag = 0x5A000000 + (t - 1);
      // --- poll: wave w reads replica w, lane l covers flags [l*4, l*4+4) ---
      const int* fp = flags + (((long)(d * 1024 + (t - 1)) * 4 + w) * 256 + l * 4);
      i32x4 fv;
      int tries = 0; bool ok;
      do {
        asm volatile("global_load_dwordx4 %0, %1, off sc0 sc1" : "=v"(fv) : "v"(fp) : "memory");
        asm volatile("s_waitcnt vmcnt(0)" ::: "memory");
        ok = (bool)__all((int)(fv.x == tag && fv.y == tag && fv.z == tag && fv.w == tag));
      } while (!ok && ++tries < (1 << 14));
      // --- one-shot A-fragment load: lane lm=b, k = kt*32 + lq*8 + 0..7 ---
      i32x4 q[8];
      #pragma unroll
      for (int i = 0; i < 8; ++i) q[i] = i32x4{0,0,0,0};
      if (bval){
        const char* dp = (const char*)(hexd + ((long)(d * 1024 + (t - 1)) * 8 + lm) * 256 + lq * 8);
#define LD(i, o) asm volatile("global_load_dwordx4 %0, %1, off offset:" #o " sc0 sc1" : "=v"(q[i]) : "v"(dp) : "memory")
        LD(0,0); LD(1,64); LD(2,128); LD(3,192); LD(4,256); LD(5,320); LD(6,384); LD(7,448);
#undef LD
        asm volatile("s_waitcnt vmcnt(0)" ::: "memory");
      }
      #pragma unroll
      for (int kt = 0; kt < 8; ++kt){
        short8 af = __builtin_bit_cast(short8, q[kt]);
        if (kt & 1) acc1 = __builtin_amdgcn_mfma_f32_16x16x32_bf16(af, bfr[kt], acc1, 0, 0, 0);
        else        acc0 = __builtin_amdgcn_mfma_f32_16x16x32_bf16(af, bfr[kt], acc0, 0, 0, 0);
      }
    }
    f32x4 asum = acc0 + acc1;
    if (l < 32){
      *(f32x4*)&gbuf[(w * 16 + lm) * 8 + lq * 4] = asum;   // C[b=lq*4+r][j=lm]
    }
    __syncthreads();   // B1
    if (tid < 128){
      const float gi = gbuf[(0 * 16 + gj) * 8 + gb] + xgi;
      const float gf = gbuf[(1 * 16 + gj) * 8 + gb] + xgf;
      const float gg = gbuf[(2 * 16 + gj) * 8 + gb] + xgg;
      const float go = gbuf[(3 * 16 + gj) * 8 + gb] + xgo;
      c_state = fsigmoid(gf) * c_state + fsigmoid(gi) * ftanhf(gg);
      const float h = fsigmoid(go) * ftanhf(c_state);
      const unsigned short hb = f2bf(h);
      hcat[(long)(gb * 1024 + t_x) * 1024 + d * 256 + g * 16 + gj] = hb;
      hT[(long)(gb * 512 + d * 256 + g * 16 + gj) * 1024 + t_x] = hb;
      hsh[gb * 16 + gj] = hb;
    }
    __syncthreads();   // B2 (hsh visible)
    if (tid < 16){
      const int b = tid >> 1, half = tid & 1;
      i32x4 dv = *(const i32x4*)((const char*)hsh + b * 32 + half * 16);
      char* sp = (char*)(hexd + ((long)(d * 1024 + t) * 8 + b) * 256 + g * 16) + half * 16;
      asm volatile("global_store_dwordx4 %0, %1, off sc0 sc1" :: "v"(sp), "v"(dv) : "memory");
      asm volatile("s_waitcnt vmcnt(0)" ::: "memory");      // release: this thread's chunk drained
      const int tg = 0x5A000000 + t;
      int* fq = flags + ((long)(d * 1024 + t) * 4) * 256 + g * 16 + tid;
      asm volatile("global_store_dword %0, %1, off sc0 sc1"             :: "v"(fq), "v"(tg) : "memory");
      asm volatile("global_store_dword %0, %1, off offset:1024 sc0 sc1" :: "v"(fq), "v"(tg) : "memory");
      asm volatile("global_store_dword %0, %1, off offset:2048 sc0 sc1" :: "v"(fq), "v"(tg) : "memory");
      asm volatile("global_store_dword %0, %1, off offset:3072 sc0 sc1" :: "v"(fq), "v"(tg) : "memory");
    }
  }
}

// ---------------- attention scores + softmax ----------------
__global__ __launch_bounds__(256) void attn_scores(
    const float* __restrict__ qk,   // [8192][64]: qp at cols 0..9, kp at cols 16..25
    const float* __restrict__ W2,   // [10]
    const int*   __restrict__ mask, // [8][1024]
    unsigned short* __restrict__ attn) // [8][1024][1024] bf16
{
  const int bt = blockIdx.x;
  const int b = bt >> 10;
  const int tid = threadIdx.x;
  __shared__ float red[256];
  float qv[10], w2[10];
  const float* qrow = qk + (long)bt * 64;
  #pragma unroll
  for (int x = 0; x < 10; ++x){ qv[x] = qrow[x]; w2[x] = W2[x]; }
  float sv[4];
  float smax = -3.4e38f;
  #pragma unroll
  for (int uu = 0; uu < 4; ++uu){
    const int u = tid + uu * 256;
    const float* krow = qk + (long)(b * 1024 + u) * 64 + 16;
    float s = 0.f;
    #pragma unroll
    for (int x = 0; x < 10; ++x) s += w2[x] * ftanhf(qv[x] + krow[x]);
    if (mask[b * 1024 + u] == 0) s = -3.0e38f;
    sv[uu] = s;
    smax = fmaxf(smax, s);
  }
  red[tid] = smax; __syncthreads();
  for (int off = 128; off > 0; off >>= 1){
    if (tid < off) red[tid] = fmaxf(red[tid], red[tid + off]);
    __syncthreads();
  }
  const float mx = red[0]; __syncthreads();
  float ev[4]; float lsum = 0.f;
  #pragma unroll
  for (int uu = 0; uu < 4; ++uu){ ev[uu] = fexp2((sv[uu] - mx) * LOG2E); lsum += ev[uu]; }
  red[tid] = lsum; __syncthreads();
  for (int off = 128; off > 0; off >>= 1){
    if (tid < off) red[tid] = red[tid] + red[tid + off];
    __syncthreads();
  }
  const float inv = frcp(red[0]);
  #pragma unroll
  for (int uu = 0; uu < 4; ++uu)
    attn[(long)bt * 1024 + tid + uu * 256] = f2bf(ev[uu] * inv);
}

// ---------------- launch ----------------
extern "C" void kernel_launch(void* const* d_in, const int* in_sizes, int n_in,
                              void* d_out, int out_size, void* d_ws, size_t ws_size,
                              hipStream_t stream) {
  (void)in_sizes; (void)n_in; (void)out_size; (void)ws_size;
  const float* x     = (const float*)d_in[0];
  const int*   mask  = (const int*)d_in[1];
  const float* Wih_f = (const float*)d_in[3];
  const float* Whh_f = (const float*)d_in[4];
  const float* bih_f = (const float*)d_in[5];
  const float* bhh_f = (const float*)d_in[6];
  const float* Wih_b = (const float*)d_in[7];
  const float* Whh_b = (const float*)d_in[8];
  const float* bih_b = (const float*)d_in[9];
  const float* bhh_b = (const float*)d_in[10];
  const float* W1    = (const float*)d_in[11];
  const float* W2    = (const float*)d_in[12];
  const float* W3    = (const float*)d_in[13];
  const float* b3    = (const float*)d_in[14];

  char* W = (char*)d_ws;
  unsigned short* x_bf    = (unsigned short*)(W + 0);            // 12,582,912
  unsigned short* wihcat  = (unsigned short*)(W + 12582912);     //  3,145,728
  unsigned short* w3bf    = (unsigned short*)(W + 15728640);     //  1,048,576
  unsigned short* w1p     = (unsigned short*)(W + 16777216);     //     65,536
  float*          bc      = (float*)        (W + 16842752);      //      8,192
  unsigned short* xg      = (unsigned short*)(W + 16850944);     // 33,554,432
  unsigned short* hexd    = (unsigned short*)(W + 50405376);     //  8,388,608
  int*            flags   = (int*)          (W + 58793984);      //  8,388,608
  unsigned short* hcat    = (unsigned short*)(W + 67182592);     // 16,777,216
  unsigned short* hT      = (unsigned short*)(W + 83959808);     //  8,388,608
  float*          qk      = (float*)        (W + 92348416);      //  2,097,152
  unsigned short* attn    = (unsigned short*)(W + 94445568);     // 16,777,216 -> total 111,222,784

  // prep
  cast_f32_bf16<<<6144, 256, 0, stream>>>(x, x_bf, 1572864);
  cast_f32_bf16<<<768,  256, 0, stream>>>(Wih_f, wihcat, 196608);
  cast_f32_bf16<<<768,  256, 0, stream>>>(Wih_b, wihcat + 786432, 196608);
  cast_f32_bf16<<<512,  256, 0, stream>>>(W3, w3bf, 131072);
  pack_w1 <<<128, 256, 0, stream>>>(W1, w1p);
  pack_bias<<<2, 1024, 0, stream>>>(bih_f, bhh_f, bih_b, bhh_b, bc);

  // xg = x @ [Wih_f;Wih_b]^T + bias  -> bf16 [8192][2048]
  gemm_abt<<<dim3(16, 64, 1), 256, 0, stream>>>(x_bf, 768, 0, wihcat, 768, 0, bc,
                                                xg, 2048, 0, 8192, 2048, 768, 1);
  // BiLSTM scan
  lstm_scan<<<32, 256, 0, stream>>>(xg, Whh_f, Whh_b, hexd, flags, hcat, hT);

  // qp/kp: hcat[:, :512] @ W1pack^T -> qk fp32 [8192][64]
  gemm_abt<<<dim3(1, 64, 1), 256, 0, stream>>>(hcat, 1024, 0, w1p, 512, 0, nullptr,
                                               qk, 64, 0, 8192, 64, 512, 0);
  // scores + softmax -> attn bf16
  attn_scores<<<8192, 256, 0, stream>>>(qk, W2, mask, attn);

  // context = attn @ h (per b): A=attn[b], B=hT[b] (512x1024) -> hcat[:, 512:]
  gemm_abt<<<dim3(4, 8, 8), 256, 0, stream>>>(attn, 1024, 1048576, hT, 1024, 524288, nullptr,
                                              (void*)(hcat + 512), 1024, 1048576, 1024, 512, 1024, 1);
  // y = [h|ctx] @ W3^T + b3 -> d_out fp32
  gemm_abt<<<dim3(4, 64, 1), 256, 0, stream>>>(hcat, 1024, 0, w3bf, 1024, 0, b3,
                                               (float*)d_out, 512, 0, 8192, 512, 1024, 0);
}

// Round 3
// 1976.671 us; speedup vs baseline: 1.7041x; 1.3144x over previous
//
#include <hip/hip_runtime.h>

typedef __attribute__((ext_vector_type(4))) float  f32x4;
typedef __attribute__((ext_vector_type(8))) short  short8;
typedef __attribute__((ext_vector_type(4))) int    i32x4;
typedef __attribute__((ext_vector_type(2))) int    i32x2;

#define LOG2E 1.4426950408889634f

__device__ __forceinline__ float fexp2(float x){ float r; asm("v_exp_f32 %0, %1" : "=v"(r) : "v"(x)); return r; }
__device__ __forceinline__ float frcp (float x){ float r; asm("v_rcp_f32 %0, %1" : "=v"(r) : "v"(x)); return r; }
__device__ __forceinline__ float fsigmoid(float x){ return frcp(1.f + fexp2(-LOG2E*x)); }
__device__ __forceinline__ float ftanhf (float x){ return 1.f - 2.f*frcp(1.f + fexp2(2.f*LOG2E*x)); }

__device__ __forceinline__ unsigned short f2bf(float f){
  unsigned u = __builtin_bit_cast(unsigned, f);
  u = u + 0x7FFFu + ((u >> 16) & 1u);
  return (unsigned short)(u >> 16);
}
__device__ __forceinline__ float bf2f(unsigned short h){
  unsigned u = ((unsigned)h) << 16;
  return __builtin_bit_cast(float, u);
}

// ---------------- prep kernels ----------------
__global__ void cast_f32_bf16(const float* __restrict__ s, unsigned short* __restrict__ d, int n4){
  int i = blockIdx.x * 256 + threadIdx.x;
  int stride = gridDim.x * 256;
  for (; i < n4; i += stride){
    float4 f = ((const float4*)s)[i];
    uint2 o;
    o.x = (unsigned)f2bf(f.x) | ((unsigned)f2bf(f.y) << 16);
    o.y = (unsigned)f2bf(f.z) | ((unsigned)f2bf(f.w) << 16);
    ((uint2*)d)[i] = o;
  }
}

__global__ void pack_w1(const float* __restrict__ W1, unsigned short* __restrict__ d){
  int i = blockIdx.x * 256 + threadIdx.x;   // 0..32767
  int r = i >> 9, c = i & 511;
  float v = 0.f;
  if (r < 10) v = W1[r * 1024 + c];
  else if (r >= 16 && r < 26) v = W1[(r - 16) * 1024 + 512 + c];
  d[i] = f2bf(v);
}

__global__ void pack_bias(const float* __restrict__ bif, const float* __restrict__ bhf,
                          const float* __restrict__ bib, const float* __restrict__ bhb,
                          float* __restrict__ d){
  int i = blockIdx.x * 1024 + threadIdx.x;
  if (i < 1024) d[i] = bif[i] + bhf[i];
  else          d[i] = bib[i - 1024] + bhb[i - 1024];
}

// ---------------- generic bf16 GEMM: C[M,N] = A[M,K] @ B[N,K]^T (+bias) ----------------
__global__ __launch_bounds__(256) void gemm_abt(
    const unsigned short* __restrict__ A, long lda, long sAz,
    const unsigned short* __restrict__ B, long ldb, long sBz,
    const float* __restrict__ bias,
    void* __restrict__ Cv, long ldc, long sCz,
    int M, int N, int K, int obf16)
{
  __shared__ __align__(16) unsigned short As[128 * 40];
  __shared__ __align__(16) unsigned short Bs[128 * 40];
  const int tid = threadIdx.x;
  const int m0 = blockIdx.y * 128;
  const int n0 = blockIdx.x * 128;
  const long z = blockIdx.z;
  A += z * sAz; B += z * sBz;
  const int w = tid >> 6, l = tid & 63;
  const int wm = (w >> 1) * 64, wn = (w & 1) * 64;
  const int lm = l & 15, lq = l >> 4;
  f32x4 acc[4][4] = {};
  const int sr = tid >> 1;
  const int sk = (tid & 1) * 16;
  const unsigned short* Aptr = A + (long)(m0 + sr) * lda + sk;
  const unsigned short* Bptr = B + (long)(n0 + sr) * ldb + sk;
  const bool bvalid = (n0 + sr) < N;
  const int KB = K >> 5;
  for (int kb = 0; kb < KB; ++kb){
    i32x4 av0 = *(const i32x4*)(Aptr);
    i32x4 av1 = *(const i32x4*)(Aptr + 8);
    i32x4 bv0 = {0,0,0,0}, bv1 = {0,0,0,0};
    if (bvalid){ bv0 = *(const i32x4*)(Bptr); bv1 = *(const i32x4*)(Bptr + 8); }
    Aptr += 32; Bptr += 32;
    __syncthreads();
    *(i32x4*)&As[sr * 40 + sk] = av0;  *(i32x4*)&As[sr * 40 + sk + 8] = av1;
    *(i32x4*)&Bs[sr * 40 + sk] = bv0;  *(i32x4*)&Bs[sr * 40 + sk + 8] = bv1;
    __syncthreads();
    const int koff = lq * 8;
    short8 af[4], bf[4];
    #pragma unroll
    for (int mt = 0; mt < 4; ++mt) af[mt] = *(short8*)&As[(wm + mt * 16 + lm) * 40 + koff];
    #pragma unroll
    for (int nt = 0; nt < 4; ++nt) bf[nt] = *(short8*)&Bs[(wn + nt * 16 + lm) * 40 + koff];
    #pragma unroll
    for (int mt = 0; mt < 4; ++mt)
      #pragma unroll
      for (int nt = 0; nt < 4; ++nt)
        acc[mt][nt] = __builtin_amdgcn_mfma_f32_16x16x32_bf16(af[mt], bf[nt], acc[mt][nt], 0, 0, 0);
  }
  #pragma unroll
  for (int mt = 0; mt < 4; ++mt){
    const int mbase = m0 + wm + mt * 16 + lq * 4;
    #pragma unroll
    for (int nt = 0; nt < 4; ++nt){
      const int n = n0 + wn + nt * 16 + lm;
      if (n < N){
        const float bv = bias ? bias[n] : 0.f;
        #pragma unroll
        for (int r = 0; r < 4; ++r){
          const float v = acc[mt][nt][r] + bv;
          const long idx = z * sCz + (long)(mbase + r) * ldc + n;
          if (obf16) ((unsigned short*)Cv)[idx] = f2bf(v);
          else       ((float*)Cv)[idx] = v;
        }
      }
    }
  }
}

// ---------------- LSTM scan (single-hop tagged exchange) ----------------
// 16 blocks x 256 threads. block = (dir d = bid&1, slice g = bid>>1 of 32 hidden units).
// Wave w = gate (i,f,g,o); wave owns 32 rows of Whh (2 n-tiles), register-resident B-frags.
// Exchange: hexd[d][t] = 1024 qwords (tag32 = 0x5A000000+t | h[b][j],h[b][j+16] as 2xbf16),
//   unit = b*128 + g*16 + (j&15). One 8B sc0sc1 store per value-pair = atomic visibility:
//   no flags, no release wait. Consumers poll the data itself with 8 coalesced dwordx4
//   loads (full 8KB tagged h); on tag match the data is already in registers; wave-private
//   LDS bounce transposes to A-frag layout (in-order DS pipe, no barrier).
__global__ __launch_bounds__(256) void lstm_scan(
    const unsigned short* __restrict__ xg,   // [8192][2048] bf16, row=b*1024+t, col=d*1024+gate*256+(g*32+j)
    const float* __restrict__ Whh_f, const float* __restrict__ Whh_b,
    unsigned long long* __restrict__ hexd,   // [2][1024][1024] tagged qwords
    unsigned short* __restrict__ hcat,       // [8][1024][1024] bf16 (cols 0..511 written here)
    unsigned short* __restrict__ hT)         // [8][512][1024] bf16 (transposed h)
{
  const int d  = blockIdx.x & 1;
  const int g  = blockIdx.x >> 1;          // 0..7
  const int tid = threadIdx.x;
  const int w  = tid >> 6;                 // gate
  const int l  = tid & 63;
  const int lm = l & 15;
  const int lq = l >> 4;
  const float* Whh = d ? Whh_b : Whh_f;

  __shared__ float gbuf[2][4][32][9];          // [parity][gate][j][b(pad 9: conflict-free reads)]
  __shared__ __align__(16) unsigned hbuf[4][8 * 136];  // per-wave h staging, stride 136 dwords/row

  // resident B fragments: wave w rows w*256 + g*32 + nt*16 + lm, k = kt*32 + lq*8 + 0..7
  short8 bfr[2][8];
  #pragma unroll
  for (int nt = 0; nt < 2; ++nt){
    const float* wr = Whh + (long)(w * 256 + g * 32 + nt * 16 + lm) * 256 + lq * 8;
    #pragma unroll
    for (int kt = 0; kt < 8; ++kt){
      float4 f0 = *(const float4*)(wr + kt * 32);
      float4 f1 = *(const float4*)(wr + kt * 32 + 4);
      i32x4 p;
      p.x = (unsigned)f2bf(f0.x) | ((unsigned)f2bf(f0.y) << 16);
      p.y = (unsigned)f2bf(f0.z) | ((unsigned)f2bf(f0.w) << 16);
      p.z = (unsigned)f2bf(f1.x) | ((unsigned)f2bf(f1.y) << 16);
      p.w = (unsigned)f2bf(f1.z) | ((unsigned)f2bf(f1.w) << 16);
      bfr[nt][kt] = __builtin_bit_cast(short8, p);
    }
  }

  const int gb = tid >> 5;        // b (0..7)
  const int gj = tid & 31;        // j local to this block's 32-unit slice
  const int c0 = (l >> 3) * 16 + (l & 7);   // scatter dword col = jA/2
  float c_state = 0.f;

  for (int t = 0; t < 1024; ++t){
    const int t_x = d ? (1023 - t) : t;
    const int par = t & 1;
    // xg prefetch (off critical path; overlaps the poll)
    float xgv0, xgv1, xgv2, xgv3;
    {
      const unsigned short* xr = xg + (long)(gb * 1024 + t_x) * 2048 + d * 1024 + g * 32 + gj;
      xgv0 = bf2f(xr[0]); xgv1 = bf2f(xr[256]); xgv2 = bf2f(xr[512]); xgv3 = bf2f(xr[768]);
    }
    f32x4 acc0 = {0.f,0.f,0.f,0.f}, acc1 = {0.f,0.f,0.f,0.f};
    if (t > 0){
      const int tag = 0x5A000000 + (t - 1);
      const char* pb  = (const char*)(hexd + (long)(d * 1024 + (t - 1)) * 1024) + l * 16;
      const char* pb2 = pb + 4096;
      i32x4 q0, q1, q2, q3, q4, q5, q6, q7;
      int tries = 0; bool ok;
      do {
        asm volatile("global_load_dwordx4 %0, %1, off sc0 sc1"             : "=v"(q0) : "v"(pb)  : "memory");
        asm volatile("global_load_dwordx4 %0, %1, off offset:1024 sc0 sc1" : "=v"(q1) : "v"(pb)  : "memory");
        asm volatile("global_load_dwordx4 %0, %1, off offset:2048 sc0 sc1" : "=v"(q2) : "v"(pb)  : "memory");
        asm volatile("global_load_dwordx4 %0, %1, off offset:3072 sc0 sc1" : "=v"(q3) : "v"(pb)  : "memory");
        asm volatile("global_load_dwordx4 %0, %1, off sc0 sc1"             : "=v"(q4) : "v"(pb2) : "memory");
        asm volatile("global_load_dwordx4 %0, %1, off offset:1024 sc0 sc1" : "=v"(q5) : "v"(pb2) : "memory");
        asm volatile("global_load_dwordx4 %0, %1, off offset:2048 sc0 sc1" : "=v"(q6) : "v"(pb2) : "memory");
        asm volatile("global_load_dwordx4 %0, %1, off offset:3072 sc0 sc1" : "=v"(q7) : "v"(pb2) : "memory");
        asm volatile("s_waitcnt vmcnt(0)" ::: "memory");
        bool my = (q0.x == tag) && (q0.z == tag) && (q1.x == tag) && (q1.z == tag)
               && (q2.x == tag) && (q2.z == tag) && (q3.x == tag) && (q3.z == tag)
               && (q4.x == tag) && (q4.z == tag) && (q5.x == tag) && (q5.z == tag)
               && (q6.x == tag) && (q6.z == tag) && (q7.x == tag) && (q7.z == tag);
        ok = (bool)__all((int)my);
      } while (!ok && ++tries < 32768);
      // scatter to wave-private hbuf: load i covers b=i; lane's units give j = jA,jA+1 and jA+16,jA+17
      unsigned* hb = &hbuf[w][0];
#define SCAT(i, Q) { \
        unsigned d0 = ((unsigned)Q.y & 0xFFFFu) | ((unsigned)Q.w << 16); \
        unsigned d1 = ((unsigned)Q.y >> 16) | ((unsigned)Q.w & 0xFFFF0000u); \
        hb[(i) * 136 + c0] = d0; hb[(i) * 136 + c0 + 8] = d1; }
      SCAT(0, q0); SCAT(1, q1); SCAT(2, q2); SCAT(3, q3);
      SCAT(4, q4); SCAT(5, q5); SCAT(6, q6); SCAT(7, q7);
#undef SCAT
      // A-frags from hbuf (same wave wrote it; DS pipe is in-order per wave) + MFMA
      #pragma unroll
      for (int kt = 0; kt < 8; ++kt){
        short8 af = *(const short8*)&hbuf[w][(lm & 7) * 136 + kt * 16 + lq * 4];
        acc0 = __builtin_amdgcn_mfma_f32_16x16x32_bf16(af, bfr[0][kt], acc0, 0, 0, 0);
        acc1 = __builtin_amdgcn_mfma_f32_16x16x32_bf16(af, bfr[1][kt], acc1, 0, 0, 0);
      }
    }
    // C[b = lq*4+r][j = nt*16+lm] -> gbuf[par][w][j][b]
    if (l < 32){
      #pragma unroll
      for (int r = 0; r < 4; ++r){
        gbuf[par][w][lm][lq * 4 + r]      = acc0[r];
        gbuf[par][w][16 + lm][lq * 4 + r] = acc1[r];
      }
    }
    __syncthreads();
    {
      const float gi = gbuf[par][0][gj][gb] + xgv0;
      const float gf = gbuf[par][1][gj][gb] + xgv1;
      const float gg = gbuf[par][2][gj][gb] + xgv2;
      const float go = gbuf[par][3][gj][gb] + xgv3;
      c_state = fsigmoid(gf) * c_state + fsigmoid(gi) * ftanhf(gg);
      const float h = fsigmoid(go) * ftanhf(c_state);
      const unsigned short hb16 = f2bf(h);
      const int other = __shfl_xor((int)hb16, 16);
      if ((gj & 16) == 0){
        i32x2 st;
        st.x = 0x5A000000 + t;
        st.y = (int)(((unsigned)hb16) | (((unsigned)other) << 16));
        unsigned long long* sp = hexd + (long)(d * 1024 + t) * 1024 + gb * 128 + g * 16 + gj;
        asm volatile("global_store_dwordx2 %0, %1, off sc0 sc1" :: "v"(sp), "v"(st) : "memory");
      }
      // off-chain output stores (no wait; drain during next poll)
      hcat[(long)(gb * 1024 + t_x) * 1024 + d * 256 + g * 32 + gj] = hb16;
      hT[(long)(gb * 512 + d * 256 + g * 32 + gj) * 1024 + t_x] = hb16;
    }
  }
}

// ---------------- attention scores + softmax ----------------
__global__ __launch_bounds__(256) void attn_scores(
    const float* __restrict__ qk,   // [8192][64]: qp at cols 0..9, kp at cols 16..25
    const float* __restrict__ W2,   // [10]
    const int*   __restrict__ mask, // [8][1024]
    unsigned short* __restrict__ attn) // [8][1024][1024] bf16
{
  const int bt = blockIdx.x;
  const int b = bt >> 10;
  const int tid = threadIdx.x;
  __shared__ float red[256];
  float qv[10], w2[10];
  const float* qrow = qk + (long)bt * 64;
  #pragma unroll
  for (int x = 0; x < 10; ++x){ qv[x] = qrow[x]; w2[x] = W2[x]; }
  float sv[4];
  float smax = -3.4e38f;
  #pragma unroll
  for (int uu = 0; uu < 4; ++uu){
    const int u = tid + uu * 256;
    const float* krow = qk + (long)(b * 1024 + u) * 64 + 16;
    float s = 0.f;
    #pragma unroll
    for (int x = 0; x < 10; ++x) s += w2[x] * ftanhf(qv[x] + krow[x]);
    if (mask[b * 1024 + u] == 0) s = -3.0e38f;
    sv[uu] = s;
    smax = fmaxf(smax, s);
  }
  red[tid] = smax; __syncthreads();
  for (int off = 128; off > 0; off >>= 1){
    if (tid < off) red[tid] = fmaxf(red[tid], red[tid + off]);
    __syncthreads();
  }
  const float mx = red[0]; __syncthreads();
  float ev[4]; float lsum = 0.f;
  #pragma unroll
  for (int uu = 0; uu < 4; ++uu){ ev[uu] = fexp2((sv[uu] - mx) * LOG2E); lsum += ev[uu]; }
  red[tid] = lsum; __syncthreads();
  for (int off = 128; off > 0; off >>= 1){
    if (tid < off) red[tid] = red[tid] + red[tid + off];
    __syncthreads();
  }
  const float inv = frcp(red[0]);
  #pragma unroll
  for (int uu = 0; uu < 4; ++uu)
    attn[(long)bt * 1024 + tid + uu * 256] = f2bf(ev[uu] * inv);
}

// ---------------- launch ----------------
extern "C" void kernel_launch(void* const* d_in, const int* in_sizes, int n_in,
                              void* d_out, int out_size, void* d_ws, size_t ws_size,
                              hipStream_t stream) {
  (void)in_sizes; (void)n_in; (void)out_size; (void)ws_size;
  const float* x     = (const float*)d_in[0];
  const int*   mask  = (const int*)d_in[1];
  const float* Wih_f = (const float*)d_in[3];
  const float* Whh_f = (const float*)d_in[4];
  const float* bih_f = (const float*)d_in[5];
  const float* bhh_f = (const float*)d_in[6];
  const float* Wih_b = (const float*)d_in[7];
  const float* Whh_b = (const float*)d_in[8];
  const float* bih_b = (const float*)d_in[9];
  const float* bhh_b = (const float*)d_in[10];
  const float* W1    = (const float*)d_in[11];
  const float* W2    = (const float*)d_in[12];
  const float* W3    = (const float*)d_in[13];
  const float* b3    = (const float*)d_in[14];

  char* W = (char*)d_ws;
  unsigned short* x_bf    = (unsigned short*)(W + 0);            // 12,582,912
  unsigned short* wihcat  = (unsigned short*)(W + 12582912);     //  3,145,728
  unsigned short* w3bf    = (unsigned short*)(W + 15728640);     //  1,048,576
  unsigned short* w1p     = (unsigned short*)(W + 16777216);     //     65,536
  float*          bc      = (float*)        (W + 16842752);      //      8,192
  unsigned short* xg      = (unsigned short*)(W + 16850944);     // 33,554,432
  unsigned long long* hexd= (unsigned long long*)(W + 50405376); // 16,777,216
  unsigned short* hcat    = (unsigned short*)(W + 67182592);     // 16,777,216
  unsigned short* hT      = (unsigned short*)(W + 83959808);     //  8,388,608
  float*          qk      = (float*)        (W + 92348416);      //  2,097,152
  unsigned short* attn    = (unsigned short*)(W + 94445568);     // 16,777,216 -> total 111,222,784

  // prep
  cast_f32_bf16<<<6144, 256, 0, stream>>>(x, x_bf, 1572864);
  cast_f32_bf16<<<768,  256, 0, stream>>>(Wih_f, wihcat, 196608);
  cast_f32_bf16<<<768,  256, 0, stream>>>(Wih_b, wihcat + 786432, 196608);
  cast_f32_bf16<<<512,  256, 0, stream>>>(W3, w3bf, 131072);
  pack_w1 <<<128, 256, 0, stream>>>(W1, w1p);
  pack_bias<<<2, 1024, 0, stream>>>(bih_f, bhh_f, bih_b, bhh_b, bc);

  // xg = x @ [Wih_f;Wih_b]^T + bias  -> bf16 [8192][2048]
  gemm_abt<<<dim3(16, 64, 1), 256, 0, stream>>>(x_bf, 768, 0, wihcat, 768, 0, bc,
                                                xg, 2048, 0, 8192, 2048, 768, 1);
  // BiLSTM scan
  lstm_scan<<<16, 256, 0, stream>>>(xg, Whh_f, Whh_b, hexd, hcat, hT);

  // qp/kp: hcat[:, :512] @ W1pack^T -> qk fp32 [8192][64]
  gemm_abt<<<dim3(1, 64, 1), 256, 0, stream>>>(hcat, 1024, 0, w1p, 512, 0, nullptr,
                                               qk, 64, 0, 8192, 64, 512, 0);
  // scores + softmax -> attn bf16
  attn_scores<<<8192, 256, 0, stream>>>(qk, W2, mask, attn);

  // context = attn @ h (per b): A=attn[b], B=hT[b] (512x1024) -> hcat[:, 512:]
  gemm_abt<<<dim3(4, 8, 8), 256, 0, stream>>>(attn, 1024, 1048576, hT, 1024, 524288, nullptr,
                                              (void*)(hcat + 512), 1024, 1048576, 1024, 512, 1024, 1);
  // y = [h|ctx] @ W3^T + b3 -> d_out fp32
  gemm_abt<<<dim3(4, 64, 1), 256, 0, stream>>>(hcat, 1024, 0, w3bf, 1024, 0, b3,
                                               (float*)d_out, 512, 0, 8192, 512, 1024, 0);
}